// Round 5
// baseline (882.998 us; speedup 1.0000x reference)
//
#include <hip/hip_runtime.h>

#define NN 100000
#define NE 1600000
#define FD 128
#define CO 10
#define BN_EPS 1e-5f
#define SCAN_B 1024
#define SCAN_NB ((NN + SCAN_B - 1) / SCAN_B)   // 98
#define NBUK ((NN + 127) / 128)                // 782 buckets of 128 nodes
#define BCAP 3072                              // mean 2048, std ~45 -> huge margin

typedef __attribute__((ext_vector_type(8))) short short8;
typedef __attribute__((ext_vector_type(4))) float f32x4;

// bf16 helpers (round-to-nearest-even)
__device__ __forceinline__ unsigned short f2bf(float f) {
  unsigned int u = __builtin_bit_cast(unsigned int, f);
  u = (u + 0x7FFFu + ((u >> 16) & 1u)) >> 16;
  return (unsigned short)u;
}
__device__ __forceinline__ float bf2f(unsigned short h) {
  unsigned int u = ((unsigned int)h) << 16;
  return __builtin_bit_cast(float, u);
}

// ---------------- bucket pass: bin edges by dst>>7, fused degree count -------
__global__ __launch_bounds__(256) void k_bucket(const int* __restrict__ src,
                                                const int* __restrict__ dst,
                                                int* __restrict__ deg_i,
                                                int* __restrict__ bcnt,
                                                uint2* __restrict__ buck) {
  int e = blockIdx.x * 256 + threadIdx.x;
  if (e >= NE) return;
  int s = src[e], d = dst[e];
  atomicAdd(&deg_i[d], 1);
  int b = d >> 7;
  int pos = atomicAdd(&bcnt[b], 1);
  buck[(size_t)b * BCAP + pos] = make_uint2((unsigned)s, (unsigned)d);
}

__global__ __launch_bounds__(256) void k_dinv(const int* __restrict__ deg_i,
                                              float* __restrict__ dinv,
                                              float* __restrict__ dinv2) {
  int i = blockIdx.x * 256 + threadIdx.x;
  if (i < NN) {
    float dv = rsqrtf((float)deg_i[i] + 1.0f);
    dinv[i] = dv;
    dinv2[i] = dv * dv;
  }
}

// ---------------- exclusive scan over deg_i -> row_start ----------------
__global__ __launch_bounds__(256) void k_scan_partial(const int* __restrict__ deg_i,
                                                      int* __restrict__ blocksum) {
  __shared__ int lds[256];
  int b = blockIdx.x, t = threadIdx.x;
  int base = b * SCAN_B + t * 4;
  int s = 0;
#pragma unroll
  for (int i = 0; i < 4; ++i) {
    int idx = base + i;
    s += (idx < NN) ? deg_i[idx] : 0;
  }
  lds[t] = s;
  __syncthreads();
  for (int off = 128; off > 0; off >>= 1) {
    if (t < off) lds[t] += lds[t + off];
    __syncthreads();
  }
  if (t == 0) blocksum[b] = lds[0];
}

__global__ void k_scan_block(int* __restrict__ blocksum) {  // 1 block, 128 threads
  __shared__ int lds[128];
  int t = threadIdx.x;
  int v = (t < SCAN_NB) ? blocksum[t] : 0;
  lds[t] = v;
  __syncthreads();
  for (int off = 1; off < 128; off <<= 1) {
    int add = (t >= off) ? lds[t - off] : 0;
    __syncthreads();
    lds[t] += add;
    __syncthreads();
  }
  if (t < SCAN_NB) blocksum[t] = lds[t] - v;  // exclusive
}

__global__ __launch_bounds__(256) void k_scan_final(const int* __restrict__ deg_i,
                                                    const int* __restrict__ blocksum,
                                                    int* __restrict__ row_start) {
  __shared__ int lds[256];
  int b = blockIdx.x, t = threadIdx.x;
  int base = b * SCAN_B + t * 4;
  int v[4];
  int s = 0;
#pragma unroll
  for (int i = 0; i < 4; ++i) {
    int idx = base + i;
    v[i] = (idx < NN) ? deg_i[idx] : 0;
    s += v[i];
  }
  lds[t] = s;
  __syncthreads();
  int mine = s;
  for (int off = 1; off < 256; off <<= 1) {
    int add = (t >= off) ? lds[t - off] : 0;
    __syncthreads();
    lds[t] += add;
    __syncthreads();
  }
  int run = lds[t] - mine + blocksum[b];
#pragma unroll
  for (int i = 0; i < 4; ++i) {
    int idx = base + i;
    if (idx < NN) {
      row_start[idx] = run;
      run += v[i];
    }
  }
  if (b == 0 && t == 0) row_start[NN] = NE;
}

// ---------------- place pass: bucket -> CSR (LDS per-node cursors) ----------
__global__ __launch_bounds__(256) void k_place(const int* __restrict__ bcnt,
                                               const uint2* __restrict__ buck,
                                               const int* __restrict__ row_start,
                                               const float* __restrict__ dinv,
                                               int* __restrict__ csr_src,
                                               float* __restrict__ csr_coef) {
  __shared__ int cnt[128];
  int b = blockIdx.x;
  int t = threadIdx.x;
  if (t < 128) cnt[t] = 0;
  __syncthreads();
  int nb = bcnt[b];
  const uint2* bp = buck + (size_t)b * BCAP;
  for (int i = t; i < nb; i += 256) {
    uint2 sd = bp[i];
    int s = (int)sd.x, d = (int)sd.y;
    int l = atomicAdd(&cnt[d & 127], 1);
    int pos = row_start[d] + l;
    csr_src[pos] = s;
    csr_coef[pos] = dinv[s] * dinv[d];
  }
}

// ---------------- BN constants ----------------
__global__ void k_prep_bn(const float* __restrict__ b, const float* __restrict__ g,
                          const float* __restrict__ be, const float* __restrict__ m,
                          const float* __restrict__ v, float* __restrict__ sc,
                          float* __restrict__ sh) {
  int f = threadIdx.x;
  if (f < FD) {
    float s = g[f] * rsqrtf(v[f] + BN_EPS);
    sc[f] = s;
    sh[f] = (b[f] - m[f]) * s + be[f];
  }
}

// ---------------- MFMA GEMM 128x128: H = X @ W (bf16x3 split, fp32-accurate) ---
// Writes f32 H and a bf16 mirror Hb (for the edge gather).
__global__ __launch_bounds__(256) void k_gemm128_mfma(const float* __restrict__ X,
                                                      const float* __restrict__ W,
                                                      float* __restrict__ H,
                                                      unsigned short* __restrict__ Hb,
                                                      int nrows) {
  __shared__ short bhi[FD * FD];  // 32 KB
  __shared__ short blo[FD * FD];  // 32 KB
  int tid = threadIdx.x;
  for (int i = tid; i < FD * FD; i += 256) {
    int k = i >> 7, n = i & 127;
    float w = W[i];
    unsigned short h = f2bf(w);
    unsigned short l = f2bf(w - bf2f(h));
    int idx = ((((k >> 5) * 8) + (n >> 4)) * 64 + ((k >> 3) & 3) * 16 + (n & 15)) * 8 + (k & 7);
    bhi[idx] = (short)h;
    blo[idx] = (short)l;
  }

  int lane = tid & 63, wv = tid >> 6;
  int lg = lane >> 4, li = lane & 15;
  int wr0 = blockIdx.x * 64 + wv * 16;
  int row = wr0 + li;
  bool ok = row < nrows;

  short8 ahi[4], alo[4];
#pragma unroll
  for (int ks = 0; ks < 4; ++ks) {
    if (ok) {
      const float* xp = X + (size_t)row * FD + ks * 32 + lg * 8;
      float4 v0 = *(const float4*)xp;
      float4 v1 = *(const float4*)(xp + 4);
      float f[8] = {v0.x, v0.y, v0.z, v0.w, v1.x, v1.y, v1.z, v1.w};
#pragma unroll
      for (int j = 0; j < 8; ++j) {
        unsigned short h = f2bf(f[j]);
        ahi[ks][j] = (short)h;
        alo[ks][j] = (short)f2bf(f[j] - bf2f(h));
      }
    } else {
#pragma unroll
      for (int j = 0; j < 8; ++j) { ahi[ks][j] = 0; alo[ks][j] = 0; }
    }
  }
  __syncthreads();

#pragma unroll
  for (int nt = 0; nt < 8; ++nt) {
    f32x4 acc = {0.f, 0.f, 0.f, 0.f};
#pragma unroll
    for (int ks = 0; ks < 4; ++ks) {
      int bidx = ((ks * 8 + nt) * 64 + lane) * 8;
      short8 bh = *(const short8*)&bhi[bidx];
      short8 bl = *(const short8*)&blo[bidx];
      acc = __builtin_amdgcn_mfma_f32_16x16x32_bf16(ahi[ks], bh, acc, 0, 0, 0);
      acc = __builtin_amdgcn_mfma_f32_16x16x32_bf16(alo[ks], bh, acc, 0, 0, 0);
      acc = __builtin_amdgcn_mfma_f32_16x16x32_bf16(ahi[ks], bl, acc, 0, 0, 0);
    }
    // C/D: col = lane&15, row = (lane>>4)*4 + reg   [m89-verified]
    int col = nt * 16 + li;
    int rb = wr0 + lg * 4;
#pragma unroll
    for (int r = 0; r < 4; ++r) {
      if (rb + r < nrows) {
        H[(size_t)(rb + r) * FD + col] = acc[r];
        Hb[(size_t)(rb + r) * FD + col] = f2bf(acc[r]);
      }
    }
  }
}

// ---------------- node-parallel gather: edges from bf16 Hb, self from f32 H ----
template <bool BN>
__global__ __launch_bounds__(256) void k_gather128(const int* __restrict__ row_start,
                                                   const int* __restrict__ csr_src,
                                                   const float* __restrict__ csr_coef,
                                                   const float* __restrict__ dinv2,
                                                   const float* __restrict__ H,
                                                   const unsigned short* __restrict__ Hb,
                                                   const float* __restrict__ sc,
                                                   const float* __restrict__ sh,
                                                   float* __restrict__ AGG) {
  int node = blockIdx.x * 4 + (threadIdx.x >> 6);
  if (node >= NN) return;
  int lane = threadIdx.x & 63;
  int beg = row_start[node], end = row_start[node + 1];
  // self-loop term in f32
  float2 s2 = ((const float2*)(H + (size_t)node * FD))[lane];
  float d2 = dinv2[node];
  float ax = s2.x * d2, ay = s2.y * d2;
  float bx = 0.f, by = 0.f;
  int e = beg;
  for (; e + 1 < end; e += 2) {
    int s0 = csr_src[e], s1 = csr_src[e + 1];
    float c0 = csr_coef[e], c1 = csr_coef[e + 1];
    unsigned int u0 = ((const unsigned int*)(Hb + (size_t)s0 * FD))[lane];
    unsigned int u1 = ((const unsigned int*)(Hb + (size_t)s1 * FD))[lane];
    ax = fmaf(__builtin_bit_cast(float, u0 << 16), c0, ax);
    ay = fmaf(__builtin_bit_cast(float, u0 & 0xFFFF0000u), c0, ay);
    bx = fmaf(__builtin_bit_cast(float, u1 << 16), c1, bx);
    by = fmaf(__builtin_bit_cast(float, u1 & 0xFFFF0000u), c1, by);
  }
  if (e < end) {
    int s0 = csr_src[e];
    float c0 = csr_coef[e];
    unsigned int u0 = ((const unsigned int*)(Hb + (size_t)s0 * FD))[lane];
    ax = fmaf(__builtin_bit_cast(float, u0 << 16), c0, ax);
    ay = fmaf(__builtin_bit_cast(float, u0 & 0xFFFF0000u), c0, ay);
  }
  float accx = ax + bx, accy = ay + by;
  if (BN) {
    float scx = sc[lane * 2], scy = sc[lane * 2 + 1];
    float shx = sh[lane * 2], shy = sh[lane * 2 + 1];
    accx = fmaxf(fmaf(accx, scx, shx), 0.f);
    accy = fmaxf(fmaf(accy, scy, shy), 0.f);
  }
  float2 o; o.x = accx; o.y = accy;
  ((float2*)(AGG + (size_t)node * FD))[lane] = o;
}

// ---------------- output GEMM 128->10 ----------------
__global__ __launch_bounds__(256) void k_gemm_out(const float* __restrict__ X,
                                                  const float* __restrict__ W3,
                                                  float* __restrict__ H3, int nrows) {
  __shared__ float ws[FD * 16];
  int tid = threadIdx.x;
  for (int i = tid; i < FD * 16; i += 256) {
    int k = i >> 4, c = i & 15;
    ws[i] = (c < CO) ? W3[k * CO + c] : 0.f;
  }
  __syncthreads();
  int grp = tid >> 4;
  int c = tid & 15;
  int r = blockIdx.x * 16 + grp;
  if (r >= nrows) return;
  const float* x = X + (size_t)r * FD;
  float acc = 0.f;
#pragma unroll
  for (int k = 0; k < FD; k += 4) {
    float4 xv = *(const float4*)&x[k];
    acc += xv.x * ws[(k + 0) * 16 + c];
    acc += xv.y * ws[(k + 1) * 16 + c];
    acc += xv.z * ws[(k + 2) * 16 + c];
    acc += xv.w * ws[(k + 3) * 16 + c];
  }
  if (c < CO) H3[(size_t)r * CO + c] = acc;
}

// ---------------- gather 10 feat, fused self-loop + bias, writes out --------
__global__ __launch_bounds__(256) void k_gather10(const int* __restrict__ row_start,
                                                  const int* __restrict__ csr_src,
                                                  const float* __restrict__ csr_coef,
                                                  const float* __restrict__ dinv2,
                                                  const float* __restrict__ H3,
                                                  const float* __restrict__ b3,
                                                  float* __restrict__ out) {
  int node = blockIdx.x * 16 + (threadIdx.x >> 4);
  if (node >= NN) return;
  int c = threadIdx.x & 15;
  int beg = row_start[node], end = row_start[node + 1];
  float acc = 0.f;
  if (c < CO) acc = H3[(size_t)node * CO + c] * dinv2[node];
  for (int e = beg; e < end; ++e) {
    int s = csr_src[e];
    float cf = csr_coef[e];
    if (c < CO) acc = fmaf(H3[(size_t)s * CO + c], cf, acc);
  }
  if (c < CO) out[(size_t)node * CO + c] = acc + b3[c];
}

// ---------------- launch ----------------
extern "C" void kernel_launch(void* const* d_in, const int* in_sizes, int n_in,
                              void* d_out, int out_size, void* d_ws, size_t ws_size,
                              hipStream_t stream) {
  const float* x = (const float*)d_in[0];
  const int* src = (const int*)d_in[1];
  const int* dst = (const int*)d_in[2];
  const float* W1 = (const float*)d_in[3];
  const float* b1 = (const float*)d_in[4];
  const float* g1 = (const float*)d_in[5];
  const float* be1 = (const float*)d_in[6];
  const float* m1 = (const float*)d_in[7];
  const float* v1 = (const float*)d_in[8];
  const float* W2 = (const float*)d_in[9];
  const float* b2 = (const float*)d_in[10];
  const float* g2 = (const float*)d_in[11];
  const float* be2 = (const float*)d_in[12];
  const float* m2 = (const float*)d_in[13];
  const float* v2 = (const float*)d_in[14];
  const float* W3 = (const float*)d_in[15];
  const float* b3 = (const float*)d_in[16];
  float* out = (float*)d_out;

  char* wsb = (char*)d_ws;
  int* deg_i = (int*)wsb;                     wsb += NN * 4;
  int* row_start = (int*)wsb;                 wsb += (NN + 1) * 4;
  int* bcnt = (int*)wsb;                      wsb += ((NBUK + 127) & ~127) * 4;
  int* blocksum = (int*)wsb;                  wsb += 128 * 4;
  float* dinv = (float*)wsb;                  wsb += NN * 4;
  float* dinv2 = (float*)wsb;                 wsb += NN * 4;
  float* sc1 = (float*)wsb;                   wsb += FD * 4;
  float* sh1 = (float*)wsb;                   wsb += FD * 4;
  float* sc2 = (float*)wsb;                   wsb += FD * 4;
  float* sh2 = (float*)wsb;                   wsb += FD * 4;
  int* csr_src = (int*)wsb;                   wsb += (size_t)NE * 4;
  float* csr_coef = (float*)wsb;              wsb += (size_t)NE * 4;
  uint2* buck = (uint2*)wsb;                  wsb += (size_t)NBUK * BCAP * 8;
  float* H = (float*)wsb;                     wsb += (size_t)NN * FD * 4;
  float* AGG = (float*)wsb;                   wsb += (size_t)NN * FD * 4;
  unsigned short* Hb = (unsigned short*)wsb;  wsb += (size_t)NN * FD * 2;
  float* H3 = H;  // layer-3 reuse (N*10 <= N*128)

  hipMemsetAsync(deg_i, 0, NN * sizeof(int), stream);
  hipMemsetAsync(bcnt, 0, NBUK * sizeof(int), stream);
  k_bucket<<<(NE + 255) / 256, 256, 0, stream>>>(src, dst, deg_i, bcnt, buck);
  k_dinv<<<(NN + 255) / 256, 256, 0, stream>>>(deg_i, dinv, dinv2);
  k_scan_partial<<<SCAN_NB, 256, 0, stream>>>(deg_i, blocksum);
  k_scan_block<<<1, 128, 0, stream>>>(blocksum);
  k_scan_final<<<SCAN_NB, 256, 0, stream>>>(deg_i, blocksum, row_start);
  k_place<<<NBUK, 256, 0, stream>>>(bcnt, buck, row_start, dinv, csr_src, csr_coef);
  k_prep_bn<<<1, 128, 0, stream>>>(b1, g1, be1, m1, v1, sc1, sh1);
  k_prep_bn<<<1, 128, 0, stream>>>(b2, g2, be2, m2, v2, sc2, sh2);

  int gemm_blocks = (NN + 63) / 64;
  int gat_blocks = (NN + 3) / 4;

  // layer 1
  k_gemm128_mfma<<<gemm_blocks, 256, 0, stream>>>(x, W1, H, Hb, NN);
  k_gather128<true><<<gat_blocks, 256, 0, stream>>>(row_start, csr_src, csr_coef,
                                                    dinv2, H, Hb, sc1, sh1, AGG);
  // layer 2
  k_gemm128_mfma<<<gemm_blocks, 256, 0, stream>>>(AGG, W2, H, Hb, NN);
  k_gather128<true><<<gat_blocks, 256, 0, stream>>>(row_start, csr_src, csr_coef,
                                                    dinv2, H, Hb, sc2, sh2, AGG);
  // layer 3
  k_gemm_out<<<(NN + 15) / 16, 256, 0, stream>>>(AGG, W3, H3, NN);
  k_gather10<<<(NN + 15) / 16, 256, 0, stream>>>(row_start, csr_src, csr_coef,
                                                 dinv2, H3, b3, out);
}

// Round 6
// 618.700 us; speedup vs baseline: 1.4272x; 1.4272x over previous
//
#include <hip/hip_runtime.h>

#define NN 100000
#define NE 1600000
#define FD 128
#define CO 10
#define BN_EPS 1e-5f
#define SCAN_B 1024
#define SCAN_NB ((NN + SCAN_B - 1) / SCAN_B)   // 98

typedef __attribute__((ext_vector_type(8))) short short8;
typedef __attribute__((ext_vector_type(4))) float f32x4;

// bf16 helpers (round-to-nearest-even)
__device__ __forceinline__ unsigned short f2bf(float f) {
  unsigned int u = __builtin_bit_cast(unsigned int, f);
  u = (u + 0x7FFFu + ((u >> 16) & 1u)) >> 16;
  return (unsigned short)u;
}
__device__ __forceinline__ float bf2f(unsigned short h) {
  unsigned int u = ((unsigned int)h) << 16;
  return __builtin_bit_cast(float, u);
}

// ---------------- degree count (int) ----------------
__global__ __launch_bounds__(256) void k_edge_deg(const int* __restrict__ dst,
                                                  int* __restrict__ deg_i) {
  int e = blockIdx.x * 256 + threadIdx.x;
  if (e < NE) atomicAdd(&deg_i[dst[e]], 1);
}

__global__ __launch_bounds__(256) void k_dinv(const int* __restrict__ deg_i,
                                              float* __restrict__ dinv) {
  int i = blockIdx.x * 256 + threadIdx.x;
  if (i < NN) dinv[i] = rsqrtf((float)deg_i[i] + 1.0f);
}

// ---------------- exclusive scan over deg_i -> row_start, cur ----------------
__global__ __launch_bounds__(256) void k_scan_partial(const int* __restrict__ deg_i,
                                                      int* __restrict__ blocksum) {
  __shared__ int lds[256];
  int b = blockIdx.x, t = threadIdx.x;
  int base = b * SCAN_B + t * 4;
  int s = 0;
#pragma unroll
  for (int i = 0; i < 4; ++i) {
    int idx = base + i;
    s += (idx < NN) ? deg_i[idx] : 0;
  }
  lds[t] = s;
  __syncthreads();
  for (int off = 128; off > 0; off >>= 1) {
    if (t < off) lds[t] += lds[t + off];
    __syncthreads();
  }
  if (t == 0) blocksum[b] = lds[0];
}

__global__ void k_scan_block(int* __restrict__ blocksum) {  // 1 block, 128 threads
  __shared__ int lds[128];
  int t = threadIdx.x;
  int v = (t < SCAN_NB) ? blocksum[t] : 0;
  lds[t] = v;
  __syncthreads();
  for (int off = 1; off < 128; off <<= 1) {
    int add = (t >= off) ? lds[t - off] : 0;
    __syncthreads();
    lds[t] += add;
    __syncthreads();
  }
  if (t < SCAN_NB) blocksum[t] = lds[t] - v;  // exclusive
}

__global__ __launch_bounds__(256) void k_scan_final(const int* __restrict__ deg_i,
                                                    const int* __restrict__ blocksum,
                                                    int* __restrict__ row_start,
                                                    int* __restrict__ cur) {
  __shared__ int lds[256];
  int b = blockIdx.x, t = threadIdx.x;
  int base = b * SCAN_B + t * 4;
  int v[4];
  int s = 0;
#pragma unroll
  for (int i = 0; i < 4; ++i) {
    int idx = base + i;
    v[i] = (idx < NN) ? deg_i[idx] : 0;
    s += v[i];
  }
  lds[t] = s;
  __syncthreads();
  int mine = s;
  for (int off = 1; off < 256; off <<= 1) {
    int add = (t >= off) ? lds[t - off] : 0;
    __syncthreads();
    lds[t] += add;
    __syncthreads();
  }
  int run = lds[t] - mine + blocksum[b];
#pragma unroll
  for (int i = 0; i < 4; ++i) {
    int idx = base + i;
    if (idx < NN) {
      row_start[idx] = run;
      cur[idx] = run;
      run += v[i];
    }
  }
  if (b == 0 && t == 0) row_start[NN] = NE;
}

// ---------------- CSR fill: src index only (coef recomputed in gather) ------
__global__ __launch_bounds__(256) void k_fill(const int* __restrict__ src,
                                              const int* __restrict__ dst,
                                              int* __restrict__ cur,
                                              int* __restrict__ csr_src) {
  int e = blockIdx.x * 256 + threadIdx.x;
  if (e >= NE) return;
  int s = src[e], d = dst[e];
  int pos = atomicAdd(&cur[d], 1);
  csr_src[pos] = s;
}

// ---------------- BN constants ----------------
__global__ void k_prep_bn(const float* __restrict__ b, const float* __restrict__ g,
                          const float* __restrict__ be, const float* __restrict__ m,
                          const float* __restrict__ v, float* __restrict__ sc,
                          float* __restrict__ sh) {
  int f = threadIdx.x;
  if (f < FD) {
    float s = g[f] * rsqrtf(v[f] + BN_EPS);
    sc[f] = s;
    sh[f] = (b[f] - m[f]) * s + be[f];
  }
}

// ---------------- MFMA GEMM 128x128: H = X @ W (bf16x3 split, fp32-accurate) ---
// Writes f32 H and a bf16 mirror Hb (for the edge gather).
__global__ __launch_bounds__(256) void k_gemm128_mfma(const float* __restrict__ X,
                                                      const float* __restrict__ W,
                                                      float* __restrict__ H,
                                                      unsigned short* __restrict__ Hb,
                                                      int nrows) {
  __shared__ short bhi[FD * FD];  // 32 KB
  __shared__ short blo[FD * FD];  // 32 KB
  int tid = threadIdx.x;
  for (int i = tid; i < FD * FD; i += 256) {
    int k = i >> 7, n = i & 127;
    float w = W[i];
    unsigned short h = f2bf(w);
    unsigned short l = f2bf(w - bf2f(h));
    int idx = ((((k >> 5) * 8) + (n >> 4)) * 64 + ((k >> 3) & 3) * 16 + (n & 15)) * 8 + (k & 7);
    bhi[idx] = (short)h;
    blo[idx] = (short)l;
  }

  int lane = tid & 63, wv = tid >> 6;
  int lg = lane >> 4, li = lane & 15;
  int wr0 = blockIdx.x * 64 + wv * 16;
  int row = wr0 + li;
  bool ok = row < nrows;

  short8 ahi[4], alo[4];
#pragma unroll
  for (int ks = 0; ks < 4; ++ks) {
    if (ok) {
      const float* xp = X + (size_t)row * FD + ks * 32 + lg * 8;
      float4 v0 = *(const float4*)xp;
      float4 v1 = *(const float4*)(xp + 4);
      float f[8] = {v0.x, v0.y, v0.z, v0.w, v1.x, v1.y, v1.z, v1.w};
#pragma unroll
      for (int j = 0; j < 8; ++j) {
        unsigned short h = f2bf(f[j]);
        ahi[ks][j] = (short)h;
        alo[ks][j] = (short)f2bf(f[j] - bf2f(h));
      }
    } else {
#pragma unroll
      for (int j = 0; j < 8; ++j) { ahi[ks][j] = 0; alo[ks][j] = 0; }
    }
  }
  __syncthreads();

#pragma unroll
  for (int nt = 0; nt < 8; ++nt) {
    f32x4 acc = {0.f, 0.f, 0.f, 0.f};
#pragma unroll
    for (int ks = 0; ks < 4; ++ks) {
      int bidx = ((ks * 8 + nt) * 64 + lane) * 8;
      short8 bh = *(const short8*)&bhi[bidx];
      short8 bl = *(const short8*)&blo[bidx];
      acc = __builtin_amdgcn_mfma_f32_16x16x32_bf16(ahi[ks], bh, acc, 0, 0, 0);
      acc = __builtin_amdgcn_mfma_f32_16x16x32_bf16(alo[ks], bh, acc, 0, 0, 0);
      acc = __builtin_amdgcn_mfma_f32_16x16x32_bf16(ahi[ks], bl, acc, 0, 0, 0);
    }
    // C/D: col = lane&15, row = (lane>>4)*4 + reg   [m89-verified]
    int col = nt * 16 + li;
    int rb = wr0 + lg * 4;
#pragma unroll
    for (int r = 0; r < 4; ++r) {
      if (rb + r < nrows) {
        H[(size_t)(rb + r) * FD + col] = acc[r];
        Hb[(size_t)(rb + r) * FD + col] = f2bf(acc[r]);
      }
    }
  }
}

// ---------------- node-parallel gather: edges from bf16 Hb, self from f32 H ----
// coef recomputed per edge: dinv[s] is L2-resident (400 KB).
template <bool BN>
__global__ __launch_bounds__(256) void k_gather128(const int* __restrict__ row_start,
                                                   const int* __restrict__ csr_src,
                                                   const float* __restrict__ dinv,
                                                   const float* __restrict__ H,
                                                   const unsigned short* __restrict__ Hb,
                                                   const float* __restrict__ sc,
                                                   const float* __restrict__ sh,
                                                   float* __restrict__ AGG) {
  int node = blockIdx.x * 4 + (threadIdx.x >> 6);
  if (node >= NN) return;
  int lane = threadIdx.x & 63;
  int beg = row_start[node], end = row_start[node + 1];
  float dv = dinv[node];
  // self-loop term in f32
  float2 s2 = ((const float2*)(H + (size_t)node * FD))[lane];
  float d2 = dv * dv;
  float ax = s2.x * d2, ay = s2.y * d2;
  float bx = 0.f, by = 0.f;
  int e = beg;
  for (; e + 1 < end; e += 2) {
    int s0 = csr_src[e], s1 = csr_src[e + 1];
    float c0 = dinv[s0] * dv, c1 = dinv[s1] * dv;
    unsigned int u0 = ((const unsigned int*)(Hb + (size_t)s0 * FD))[lane];
    unsigned int u1 = ((const unsigned int*)(Hb + (size_t)s1 * FD))[lane];
    ax = fmaf(__builtin_bit_cast(float, u0 << 16), c0, ax);
    ay = fmaf(__builtin_bit_cast(float, u0 & 0xFFFF0000u), c0, ay);
    bx = fmaf(__builtin_bit_cast(float, u1 << 16), c1, bx);
    by = fmaf(__builtin_bit_cast(float, u1 & 0xFFFF0000u), c1, by);
  }
  if (e < end) {
    int s0 = csr_src[e];
    float c0 = dinv[s0] * dv;
    unsigned int u0 = ((const unsigned int*)(Hb + (size_t)s0 * FD))[lane];
    ax = fmaf(__builtin_bit_cast(float, u0 << 16), c0, ax);
    ay = fmaf(__builtin_bit_cast(float, u0 & 0xFFFF0000u), c0, ay);
  }
  float accx = ax + bx, accy = ay + by;
  if (BN) {
    float scx = sc[lane * 2], scy = sc[lane * 2 + 1];
    float shx = sh[lane * 2], shy = sh[lane * 2 + 1];
    accx = fmaxf(fmaf(accx, scx, shx), 0.f);
    accy = fmaxf(fmaf(accy, scy, shy), 0.f);
  }
  float2 o; o.x = accx; o.y = accy;
  ((float2*)(AGG + (size_t)node * FD))[lane] = o;
}

// ---------------- output GEMM 128->10 ----------------
__global__ __launch_bounds__(256) void k_gemm_out(const float* __restrict__ X,
                                                  const float* __restrict__ W3,
                                                  float* __restrict__ H3, int nrows) {
  __shared__ float ws[FD * 16];
  int tid = threadIdx.x;
  for (int i = tid; i < FD * 16; i += 256) {
    int k = i >> 4, c = i & 15;
    ws[i] = (c < CO) ? W3[k * CO + c] : 0.f;
  }
  __syncthreads();
  int grp = tid >> 4;
  int c = tid & 15;
  int r = blockIdx.x * 16 + grp;
  if (r >= nrows) return;
  const float* x = X + (size_t)r * FD;
  float acc = 0.f;
#pragma unroll
  for (int k = 0; k < FD; k += 4) {
    float4 xv = *(const float4*)&x[k];
    acc += xv.x * ws[(k + 0) * 16 + c];
    acc += xv.y * ws[(k + 1) * 16 + c];
    acc += xv.z * ws[(k + 2) * 16 + c];
    acc += xv.w * ws[(k + 3) * 16 + c];
  }
  if (c < CO) H3[(size_t)r * CO + c] = acc;
}

// ---------------- gather 10 feat, fused self-loop + bias, writes out --------
__global__ __launch_bounds__(256) void k_gather10(const int* __restrict__ row_start,
                                                  const int* __restrict__ csr_src,
                                                  const float* __restrict__ dinv,
                                                  const float* __restrict__ H3,
                                                  const float* __restrict__ b3,
                                                  float* __restrict__ out) {
  int node = blockIdx.x * 16 + (threadIdx.x >> 4);
  if (node >= NN) return;
  int c = threadIdx.x & 15;
  int beg = row_start[node], end = row_start[node + 1];
  float dv = dinv[node];
  float acc = 0.f;
  if (c < CO) acc = H3[(size_t)node * CO + c] * (dv * dv);
  for (int e = beg; e < end; ++e) {
    int s = csr_src[e];
    float cf = dinv[s] * dv;
    if (c < CO) acc = fmaf(H3[(size_t)s * CO + c], cf, acc);
  }
  if (c < CO) out[(size_t)node * CO + c] = acc + b3[c];
}

// ---------------- launch ----------------
extern "C" void kernel_launch(void* const* d_in, const int* in_sizes, int n_in,
                              void* d_out, int out_size, void* d_ws, size_t ws_size,
                              hipStream_t stream) {
  const float* x = (const float*)d_in[0];
  const int* src = (const int*)d_in[1];
  const int* dst = (const int*)d_in[2];
  const float* W1 = (const float*)d_in[3];
  const float* b1 = (const float*)d_in[4];
  const float* g1 = (const float*)d_in[5];
  const float* be1 = (const float*)d_in[6];
  const float* m1 = (const float*)d_in[7];
  const float* v1 = (const float*)d_in[8];
  const float* W2 = (const float*)d_in[9];
  const float* b2 = (const float*)d_in[10];
  const float* g2 = (const float*)d_in[11];
  const float* be2 = (const float*)d_in[12];
  const float* m2 = (const float*)d_in[13];
  const float* v2 = (const float*)d_in[14];
  const float* W3 = (const float*)d_in[15];
  const float* b3 = (const float*)d_in[16];
  float* out = (float*)d_out;

  char* wsb = (char*)d_ws;
  int* deg_i = (int*)wsb;                     wsb += NN * 4;
  int* row_start = (int*)wsb;                 wsb += (NN + 1) * 4;
  int* cur = (int*)wsb;                       wsb += NN * 4;
  int* blocksum = (int*)wsb;                  wsb += 128 * 4;
  float* dinv = (float*)wsb;                  wsb += NN * 4;
  float* sc1 = (float*)wsb;                   wsb += FD * 4;
  float* sh1 = (float*)wsb;                   wsb += FD * 4;
  float* sc2 = (float*)wsb;                   wsb += FD * 4;
  float* sh2 = (float*)wsb;                   wsb += FD * 4;
  int* csr_src = (int*)wsb;                   wsb += (size_t)NE * 4;
  float* H = (float*)wsb;                     wsb += (size_t)NN * FD * 4;
  float* AGG = (float*)wsb;                   wsb += (size_t)NN * FD * 4;
  unsigned short* Hb = (unsigned short*)wsb;  wsb += (size_t)NN * FD * 2;
  float* H3 = H;  // layer-3 reuse (N*10 <= N*128)

  hipMemsetAsync(deg_i, 0, NN * sizeof(int), stream);
  k_edge_deg<<<(NE + 255) / 256, 256, 0, stream>>>(dst, deg_i);
  k_dinv<<<(NN + 255) / 256, 256, 0, stream>>>(deg_i, dinv);
  k_scan_partial<<<SCAN_NB, 256, 0, stream>>>(deg_i, blocksum);
  k_scan_block<<<1, 128, 0, stream>>>(blocksum);
  k_scan_final<<<SCAN_NB, 256, 0, stream>>>(deg_i, blocksum, row_start, cur);
  k_fill<<<(NE + 255) / 256, 256, 0, stream>>>(src, dst, cur, csr_src);
  k_prep_bn<<<1, 128, 0, stream>>>(b1, g1, be1, m1, v1, sc1, sh1);
  k_prep_bn<<<1, 128, 0, stream>>>(b2, g2, be2, m2, v2, sc2, sh2);

  int gemm_blocks = (NN + 63) / 64;
  int gat_blocks = (NN + 3) / 4;

  // layer 1
  k_gemm128_mfma<<<gemm_blocks, 256, 0, stream>>>(x, W1, H, Hb, NN);
  k_gather128<true><<<gat_blocks, 256, 0, stream>>>(row_start, csr_src, dinv,
                                                    H, Hb, sc1, sh1, AGG);
  // layer 2
  k_gemm128_mfma<<<gemm_blocks, 256, 0, stream>>>(AGG, W2, H, Hb, NN);
  k_gather128<true><<<gat_blocks, 256, 0, stream>>>(row_start, csr_src, dinv,
                                                    H, Hb, sc2, sh2, AGG);
  // layer 3
  k_gemm_out<<<(NN + 15) / 16, 256, 0, stream>>>(AGG, W3, H3, NN);
  k_gather10<<<(NN + 15) / 16, 256, 0, stream>>>(row_start, csr_src, dinv,
                                                 H3, b3, out);
}

// Round 7
// 477.262 us; speedup vs baseline: 1.8501x; 1.2964x over previous
//
#include <hip/hip_runtime.h>

#define NN 100000
#define NE 1600000
#define FD 128
#define CO 10
#define BN_EPS 1e-5f
#define SCAN_B 1024
#define SCAN_NB ((NN + SCAN_B - 1) / SCAN_B)   // 98
#define NBUK ((NN + 127) / 128)                // 782 buckets of 128 nodes
#define BCAP 3072                              // max bucket ~2300 (5 sigma) < 3072
#define SEGE 4096
#define NSEG ((NE + SEGE - 1) / SEGE)          // 391

typedef __attribute__((ext_vector_type(8))) short short8;
typedef __attribute__((ext_vector_type(4))) float f32x4;

// bf16 helpers (round-to-nearest-even)
__device__ __forceinline__ unsigned short f2bf(float f) {
  unsigned int u = __builtin_bit_cast(unsigned int, f);
  u = (u + 0x7FFFu + ((u >> 16) & 1u)) >> 16;
  return (unsigned short)u;
}
__device__ __forceinline__ float bf2f(unsigned short h) {
  unsigned int u = ((unsigned int)h) << 16;
  return __builtin_bit_cast(float, u);
}

// ---------------- bucket pass: LDS-aggregated counting sort by dst>>7 -------
// bcnt is line-padded (stride 16 ints) to avoid false sharing.
__global__ __launch_bounds__(256) void k_bucket2(const int* __restrict__ src,
                                                 const int* __restrict__ dst,
                                                 int* __restrict__ bcnt,
                                                 uint2* __restrict__ buck) {
  __shared__ int hist[NBUK];
  __shared__ int base[NBUK];
  int b = blockIdx.x, t = threadIdx.x;
  for (int i = t; i < NBUK; i += 256) hist[i] = 0;
  __syncthreads();
  int e0 = b * SEGE, e1 = min(e0 + SEGE, NE);
  for (int e = e0 + t; e < e1; e += 256) {
    atomicAdd(&hist[dst[e] >> 7], 1);
  }
  __syncthreads();
  for (int i = t; i < NBUK; i += 256) {
    int h = hist[i];
    base[i] = h ? atomicAdd(&bcnt[i * 16], h) : 0;
  }
  __syncthreads();
  for (int e = e0 + t; e < e1; e += 256) {
    int s = src[e], d = dst[e];
    int bk = d >> 7;
    int slot = atomicAdd(&base[bk], 1);
    buck[(size_t)bk * BCAP + slot] = make_uint2((unsigned)s, (unsigned)d);
  }
}

// ---------------- per-bucket degree count (sequential reads, LDS histogram) --
__global__ __launch_bounds__(256) void k_bdeg(const int* __restrict__ bcnt,
                                              const uint2* __restrict__ buck,
                                              int* __restrict__ deg_i) {
  __shared__ int cnt[128];
  int b = blockIdx.x, t = threadIdx.x;
  if (t < 128) cnt[t] = 0;
  __syncthreads();
  int nb = bcnt[b * 16];
  const uint2* bp = buck + (size_t)b * BCAP;
  for (int i = t; i < nb; i += 256) atomicAdd(&cnt[bp[i].y & 127], 1);
  __syncthreads();
  int node = b * 128 + t;
  if (t < 128 && node < NN) deg_i[node] = cnt[t];
}

__global__ __launch_bounds__(256) void k_dinv(const int* __restrict__ deg_i,
                                              float* __restrict__ dinv) {
  int i = blockIdx.x * 256 + threadIdx.x;
  if (i < NN) dinv[i] = rsqrtf((float)deg_i[i] + 1.0f);
}

// ---------------- exclusive scan over deg_i -> row_start ----------------
__global__ __launch_bounds__(256) void k_scan_partial(const int* __restrict__ deg_i,
                                                      int* __restrict__ blocksum) {
  __shared__ int lds[256];
  int b = blockIdx.x, t = threadIdx.x;
  int base = b * SCAN_B + t * 4;
  int s = 0;
#pragma unroll
  for (int i = 0; i < 4; ++i) {
    int idx = base + i;
    s += (idx < NN) ? deg_i[idx] : 0;
  }
  lds[t] = s;
  __syncthreads();
  for (int off = 128; off > 0; off >>= 1) {
    if (t < off) lds[t] += lds[t + off];
    __syncthreads();
  }
  if (t == 0) blocksum[b] = lds[0];
}

__global__ void k_scan_block(int* __restrict__ blocksum) {  // 1 block, 128 threads
  __shared__ int lds[128];
  int t = threadIdx.x;
  int v = (t < SCAN_NB) ? blocksum[t] : 0;
  lds[t] = v;
  __syncthreads();
  for (int off = 1; off < 128; off <<= 1) {
    int add = (t >= off) ? lds[t - off] : 0;
    __syncthreads();
    lds[t] += add;
    __syncthreads();
  }
  if (t < SCAN_NB) blocksum[t] = lds[t] - v;  // exclusive
}

__global__ __launch_bounds__(256) void k_scan_final(const int* __restrict__ deg_i,
                                                    const int* __restrict__ blocksum,
                                                    int* __restrict__ row_start) {
  __shared__ int lds[256];
  int b = blockIdx.x, t = threadIdx.x;
  int base = b * SCAN_B + t * 4;
  int v[4];
  int s = 0;
#pragma unroll
  for (int i = 0; i < 4; ++i) {
    int idx = base + i;
    v[i] = (idx < NN) ? deg_i[idx] : 0;
    s += v[i];
  }
  lds[t] = s;
  __syncthreads();
  int mine = s;
  for (int off = 1; off < 256; off <<= 1) {
    int add = (t >= off) ? lds[t - off] : 0;
    __syncthreads();
    lds[t] += add;
    __syncthreads();
  }
  int run = lds[t] - mine + blocksum[b];
#pragma unroll
  for (int i = 0; i < 4; ++i) {
    int idx = base + i;
    if (idx < NN) {
      row_start[idx] = run;
      run += v[i];
    }
  }
  if (b == 0 && t == 0) row_start[NN] = NE;
}

// ---------------- place pass: bucket -> CSR (LDS per-node cursors) ----------
__global__ __launch_bounds__(256) void k_place(const int* __restrict__ bcnt,
                                               const uint2* __restrict__ buck,
                                               const int* __restrict__ row_start,
                                               int* __restrict__ csr_src) {
  __shared__ int cnt[128];
  int b = blockIdx.x, t = threadIdx.x;
  if (t < 128) cnt[t] = 0;
  __syncthreads();
  int nb = bcnt[b * 16];
  const uint2* bp = buck + (size_t)b * BCAP;
  for (int i = t; i < nb; i += 256) {
    uint2 sd = bp[i];
    int d = (int)sd.y;
    int l = atomicAdd(&cnt[d & 127], 1);
    csr_src[row_start[d] + l] = (int)sd.x;
  }
}

// ---------------- BN constants ----------------
__global__ void k_prep_bn(const float* __restrict__ b, const float* __restrict__ g,
                          const float* __restrict__ be, const float* __restrict__ m,
                          const float* __restrict__ v, float* __restrict__ sc,
                          float* __restrict__ sh) {
  int f = threadIdx.x;
  if (f < FD) {
    float s = g[f] * rsqrtf(v[f] + BN_EPS);
    sc[f] = s;
    sh[f] = (b[f] - m[f]) * s + be[f];
  }
}

// ---------------- MFMA GEMM 128x128: H = X @ W (bf16x3 split, fp32-accurate) ---
__global__ __launch_bounds__(256) void k_gemm128_mfma(const float* __restrict__ X,
                                                      const float* __restrict__ W,
                                                      float* __restrict__ H,
                                                      unsigned short* __restrict__ Hb,
                                                      int nrows) {
  __shared__ short bhi[FD * FD];  // 32 KB
  __shared__ short blo[FD * FD];  // 32 KB
  int tid = threadIdx.x;
  for (int i = tid; i < FD * FD; i += 256) {
    int k = i >> 7, n = i & 127;
    float w = W[i];
    unsigned short h = f2bf(w);
    unsigned short l = f2bf(w - bf2f(h));
    int idx = ((((k >> 5) * 8) + (n >> 4)) * 64 + ((k >> 3) & 3) * 16 + (n & 15)) * 8 + (k & 7);
    bhi[idx] = (short)h;
    blo[idx] = (short)l;
  }

  int lane = tid & 63, wv = tid >> 6;
  int lg = lane >> 4, li = lane & 15;
  int wr0 = blockIdx.x * 64 + wv * 16;
  int row = wr0 + li;
  bool ok = row < nrows;

  short8 ahi[4], alo[4];
#pragma unroll
  for (int ks = 0; ks < 4; ++ks) {
    if (ok) {
      const float* xp = X + (size_t)row * FD + ks * 32 + lg * 8;
      float4 v0 = *(const float4*)xp;
      float4 v1 = *(const float4*)(xp + 4);
      float f[8] = {v0.x, v0.y, v0.z, v0.w, v1.x, v1.y, v1.z, v1.w};
#pragma unroll
      for (int j = 0; j < 8; ++j) {
        unsigned short h = f2bf(f[j]);
        ahi[ks][j] = (short)h;
        alo[ks][j] = (short)f2bf(f[j] - bf2f(h));
      }
    } else {
#pragma unroll
      for (int j = 0; j < 8; ++j) { ahi[ks][j] = 0; alo[ks][j] = 0; }
    }
  }
  __syncthreads();

#pragma unroll
  for (int nt = 0; nt < 8; ++nt) {
    f32x4 acc = {0.f, 0.f, 0.f, 0.f};
#pragma unroll
    for (int ks = 0; ks < 4; ++ks) {
      int bidx = ((ks * 8 + nt) * 64 + lane) * 8;
      short8 bh = *(const short8*)&bhi[bidx];
      short8 bl = *(const short8*)&blo[bidx];
      acc = __builtin_amdgcn_mfma_f32_16x16x32_bf16(ahi[ks], bh, acc, 0, 0, 0);
      acc = __builtin_amdgcn_mfma_f32_16x16x32_bf16(alo[ks], bh, acc, 0, 0, 0);
      acc = __builtin_amdgcn_mfma_f32_16x16x32_bf16(ahi[ks], bl, acc, 0, 0, 0);
    }
    // C/D: col = lane&15, row = (lane>>4)*4 + reg   [m89-verified]
    int col = nt * 16 + li;
    int rb = wr0 + lg * 4;
#pragma unroll
    for (int r = 0; r < 4; ++r) {
      if (rb + r < nrows) {
        H[(size_t)(rb + r) * FD + col] = acc[r];
        Hb[(size_t)(rb + r) * FD + col] = f2bf(acc[r]);
      }
    }
  }
}

// ---------------- node-parallel gather: edges from bf16 Hb, self from f32 H ----
template <bool BN>
__global__ __launch_bounds__(256) void k_gather128(const int* __restrict__ row_start,
                                                   const int* __restrict__ csr_src,
                                                   const float* __restrict__ dinv,
                                                   const float* __restrict__ H,
                                                   const unsigned short* __restrict__ Hb,
                                                   const float* __restrict__ sc,
                                                   const float* __restrict__ sh,
                                                   float* __restrict__ AGG) {
  int node = blockIdx.x * 4 + (threadIdx.x >> 6);
  if (node >= NN) return;
  int lane = threadIdx.x & 63;
  int beg = row_start[node], end = row_start[node + 1];
  float dv = dinv[node];
  float2 s2 = ((const float2*)(H + (size_t)node * FD))[lane];
  float d2 = dv * dv;
  float ax = s2.x * d2, ay = s2.y * d2;
  float bx = 0.f, by = 0.f;
  int e = beg;
  for (; e + 1 < end; e += 2) {
    int s0 = csr_src[e], s1 = csr_src[e + 1];
    float c0 = dinv[s0] * dv, c1 = dinv[s1] * dv;
    unsigned int u0 = ((const unsigned int*)(Hb + (size_t)s0 * FD))[lane];
    unsigned int u1 = ((const unsigned int*)(Hb + (size_t)s1 * FD))[lane];
    ax = fmaf(__builtin_bit_cast(float, u0 << 16), c0, ax);
    ay = fmaf(__builtin_bit_cast(float, u0 & 0xFFFF0000u), c0, ay);
    bx = fmaf(__builtin_bit_cast(float, u1 << 16), c1, bx);
    by = fmaf(__builtin_bit_cast(float, u1 & 0xFFFF0000u), c1, by);
  }
  if (e < end) {
    int s0 = csr_src[e];
    float c0 = dinv[s0] * dv;
    unsigned int u0 = ((const unsigned int*)(Hb + (size_t)s0 * FD))[lane];
    ax = fmaf(__builtin_bit_cast(float, u0 << 16), c0, ax);
    ay = fmaf(__builtin_bit_cast(float, u0 & 0xFFFF0000u), c0, ay);
  }
  float accx = ax + bx, accy = ay + by;
  if (BN) {
    float scx = sc[lane * 2], scy = sc[lane * 2 + 1];
    float shx = sh[lane * 2], shy = sh[lane * 2 + 1];
    accx = fmaxf(fmaf(accx, scx, shx), 0.f);
    accy = fmaxf(fmaf(accy, scy, shy), 0.f);
  }
  float2 o; o.x = accx; o.y = accy;
  ((float2*)(AGG + (size_t)node * FD))[lane] = o;
}

// ---------------- output GEMM 128->10 ----------------
__global__ __launch_bounds__(256) void k_gemm_out(const float* __restrict__ X,
                                                  const float* __restrict__ W3,
                                                  float* __restrict__ H3, int nrows) {
  __shared__ float ws[FD * 16];
  int tid = threadIdx.x;
  for (int i = tid; i < FD * 16; i += 256) {
    int k = i >> 4, c = i & 15;
    ws[i] = (c < CO) ? W3[k * CO + c] : 0.f;
  }
  __syncthreads();
  int grp = tid >> 4;
  int c = tid & 15;
  int r = blockIdx.x * 16 + grp;
  if (r >= nrows) return;
  const float* x = X + (size_t)r * FD;
  float acc = 0.f;
#pragma unroll
  for (int k = 0; k < FD; k += 4) {
    float4 xv = *(const float4*)&x[k];
    acc += xv.x * ws[(k + 0) * 16 + c];
    acc += xv.y * ws[(k + 1) * 16 + c];
    acc += xv.z * ws[(k + 2) * 16 + c];
    acc += xv.w * ws[(k + 3) * 16 + c];
  }
  if (c < CO) H3[(size_t)r * CO + c] = acc;
}

// ---------------- gather 10 feat, fused self-loop + bias, writes out --------
__global__ __launch_bounds__(256) void k_gather10(const int* __restrict__ row_start,
                                                  const int* __restrict__ csr_src,
                                                  const float* __restrict__ dinv,
                                                  const float* __restrict__ H3,
                                                  const float* __restrict__ b3,
                                                  float* __restrict__ out) {
  int node = blockIdx.x * 16 + (threadIdx.x >> 4);
  if (node >= NN) return;
  int c = threadIdx.x & 15;
  int beg = row_start[node], end = row_start[node + 1];
  float dv = dinv[node];
  float acc = 0.f;
  if (c < CO) acc = H3[(size_t)node * CO + c] * (dv * dv);
  for (int e = beg; e < end; ++e) {
    int s = csr_src[e];
    float cf = dinv[s] * dv;
    if (c < CO) acc = fmaf(H3[(size_t)s * CO + c], cf, acc);
  }
  if (c < CO) out[(size_t)node * CO + c] = acc + b3[c];
}

// ---------------- launch ----------------
extern "C" void kernel_launch(void* const* d_in, const int* in_sizes, int n_in,
                              void* d_out, int out_size, void* d_ws, size_t ws_size,
                              hipStream_t stream) {
  const float* x = (const float*)d_in[0];
  const int* src = (const int*)d_in[1];
  const int* dst = (const int*)d_in[2];
  const float* W1 = (const float*)d_in[3];
  const float* b1 = (const float*)d_in[4];
  const float* g1 = (const float*)d_in[5];
  const float* be1 = (const float*)d_in[6];
  const float* m1 = (const float*)d_in[7];
  const float* v1 = (const float*)d_in[8];
  const float* W2 = (const float*)d_in[9];
  const float* b2 = (const float*)d_in[10];
  const float* g2 = (const float*)d_in[11];
  const float* be2 = (const float*)d_in[12];
  const float* m2 = (const float*)d_in[13];
  const float* v2 = (const float*)d_in[14];
  const float* W3 = (const float*)d_in[15];
  const float* b3 = (const float*)d_in[16];
  float* out = (float*)d_out;

  char* wsb = (char*)d_ws;
  int* deg_i = (int*)wsb;                     wsb += NN * 4;
  int* row_start = (int*)wsb;                 wsb += (NN + 1) * 4;
  int* bcnt = (int*)wsb;                      wsb += (size_t)NBUK * 16 * 4;  // line-padded
  int* blocksum = (int*)wsb;                  wsb += 128 * 4;
  float* dinv = (float*)wsb;                  wsb += NN * 4;
  float* sc1 = (float*)wsb;                   wsb += FD * 4;
  float* sh1 = (float*)wsb;                   wsb += FD * 4;
  float* sc2 = (float*)wsb;                   wsb += FD * 4;
  float* sh2 = (float*)wsb;                   wsb += FD * 4;
  int* csr_src = (int*)wsb;                   wsb += (size_t)NE * 4;
  uint2* buck = (uint2*)wsb;                  wsb += (size_t)NBUK * BCAP * 8;
  float* H = (float*)wsb;                     wsb += (size_t)NN * FD * 4;
  float* AGG = (float*)wsb;                   wsb += (size_t)NN * FD * 4;
  unsigned short* Hb = (unsigned short*)wsb;  wsb += (size_t)NN * FD * 2;
  float* H3 = H;  // layer-3 reuse (N*10 <= N*128)

  hipMemsetAsync(bcnt, 0, (size_t)NBUK * 16 * 4, stream);
  k_bucket2<<<NSEG, 256, 0, stream>>>(src, dst, bcnt, buck);
  k_bdeg<<<NBUK, 256, 0, stream>>>(bcnt, buck, deg_i);
  k_dinv<<<(NN + 255) / 256, 256, 0, stream>>>(deg_i, dinv);
  k_scan_partial<<<SCAN_NB, 256, 0, stream>>>(deg_i, blocksum);
  k_scan_block<<<1, 128, 0, stream>>>(blocksum);
  k_scan_final<<<SCAN_NB, 256, 0, stream>>>(deg_i, blocksum, row_start);
  k_place<<<NBUK, 256, 0, stream>>>(bcnt, buck, row_start, csr_src);
  k_prep_bn<<<1, 128, 0, stream>>>(b1, g1, be1, m1, v1, sc1, sh1);
  k_prep_bn<<<1, 128, 0, stream>>>(b2, g2, be2, m2, v2, sc2, sh2);

  int gemm_blocks = (NN + 63) / 64;
  int gat_blocks = (NN + 3) / 4;

  // layer 1
  k_gemm128_mfma<<<gemm_blocks, 256, 0, stream>>>(x, W1, H, Hb, NN);
  k_gather128<true><<<gat_blocks, 256, 0, stream>>>(row_start, csr_src, dinv,
                                                    H, Hb, sc1, sh1, AGG);
  // layer 2
  k_gemm128_mfma<<<gemm_blocks, 256, 0, stream>>>(AGG, W2, H, Hb, NN);
  k_gather128<true><<<gat_blocks, 256, 0, stream>>>(row_start, csr_src, dinv,
                                                    H, Hb, sc2, sh2, AGG);
  // layer 3
  k_gemm_out<<<(NN + 15) / 16, 256, 0, stream>>>(AGG, W3, H3, NN);
  k_gather10<<<(NN + 15) / 16, 256, 0, stream>>>(row_start, csr_src, dinv,
                                                 H3, b3, out);
}